// Round 1
// baseline (2057.258 us; speedup 1.0000x reference)
//
#include <hip/hip_runtime.h>
#include <math.h>

#define NB 32
#define NC 96
#define NT 256
#define NV 25
#define NBC 24
#define NE 24
#define CV (NC * NV)          // 2400
#define EV (NE * NV)          // 600

__device__ __forceinline__ float hswish(float x) {
    return x * fminf(fmaxf(x + 3.f, 0.f), 6.f) * (1.f / 6.f);
}
__device__ __forceinline__ float bnval(float x, const float* p, int n, int c) {
    // p layout [4][n]: gamma, beta, rm, rv
    return (x - p[2 * n + c]) * p[c] * rsqrtf(p[3 * n + c] + 1e-5f) + p[n + c];
}

// ---- K1a: xmean[b,c,v] = mean_t x[b,c,t,v] ----
__global__ __launch_bounds__(256) void k_mean(const float* __restrict__ x,
                                              float* __restrict__ xm) {
    int bc = blockIdx.x;          // b*NC + c
    int tid = threadIdx.x;        // == t (NT == 256)
    const float* xp = x + (size_t)bc * NT * NV + (size_t)tid * NV;
    float a[NV];
#pragma unroll
    for (int v = 0; v < NV; ++v) a[v] = xp[v];
    __shared__ float part[4][NV];
    int lane = tid & 63, wid = tid >> 6;
#pragma unroll
    for (int v = 0; v < NV; ++v) {
        float val = a[v];
        for (int off = 32; off > 0; off >>= 1) val += __shfl_down(val, off, 64);
        if (lane == 0) part[wid][v] = val;
    }
    __syncthreads();
    if (tid < NV) {
        float s = part[0][tid] + part[1][tid] + part[2][tid] + part[3][tid];
        xm[bc * NV + tid] = s * (1.0f / NT);
    }
}

// ---- K1b: dynamic adjacency A_dyn[b,v,w] ----
__global__ __launch_bounds__(256) void k_adyn(const float* __restrict__ xm,
                                              const float* __restrict__ Wp,
                                              const int* __restrict__ intra,
                                              const int* __restrict__ inter,
                                              float* __restrict__ Ad) {
    int b = blockIdx.x, tid = threadIdx.x;
    __shared__ float xms[CV];
    __shared__ float embs[EV];
    __shared__ float nrm[NV];
    for (int i = tid; i < CV; i += 256) xms[i] = xm[b * CV + i];
    __syncthreads();
    for (int i = tid; i < EV; i += 256) {
        int e = i / NV, v = i % NV;
        int iv = intra[v], ev2 = inter[v];
        float acc = 0.f;
        for (int c = 0; c < NC; ++c) {
            int s0 = (c < NC / 2) ? iv : ev2;
            int col = (s0 + c) % NV;
            acc = fmaf(xms[c * NV + col], Wp[e * NC + c], acc);
        }
        embs[e * NV + v] = acc;
    }
    __syncthreads();
    if (tid < NV) {
        float acc = 0.f;
        for (int e = 0; e < NE; ++e) {
            float t = embs[e * NV + tid];
            acc = fmaf(t, t, acc);
        }
        nrm[tid] = sqrtf(acc) + 1e-12f;
    }
    __syncthreads();
    for (int i = tid; i < NV * NV; i += 256) {
        int v = i / NV, w = i % NV;
        float acc = 0.f;
        for (int e = 0; e < NE; ++e)
            acc = fmaf(embs[e * NV + v], embs[e * NV + w], acc);
        Ad[b * NV * NV + i] = acc / (nrm[v] * nrm[w]);
    }
}

// ---- K2: GCN main: per (b,t) tile -> x3 = hswish(bn(y)) ----
__global__ __launch_bounds__(256) void k_gcn(const float* __restrict__ x,
                                             const int* __restrict__ intra,
                                             const int* __restrict__ inter,
                                             const float* __restrict__ Agcn,
                                             const float* __restrict__ Wgcn,
                                             const float* __restrict__ Wadyn,
                                             const float* __restrict__ gate,
                                             const float* __restrict__ gbn,
                                             const float* __restrict__ Ad,
                                             float* __restrict__ x3) {
    int t = blockIdx.x % NT, b = blockIdx.x / NT;
    int tid = threadIdx.x;
    __shared__ float Xs[CV];
    __shared__ float Zs[4 * CV];
    float sg = 1.f / (1.f + expf(-gate[0]));
    for (int i = tid; i < CV; i += 256) {
        int c = i / NV, v = i % NV;
        int s0 = (c < NC / 2) ? intra[v] : inter[v];
        int col = (s0 + c) % NV;
        Xs[i] = x[(((size_t)b * NC + c) * NT + t) * NV + col];
    }
    __syncthreads();
    for (int i = tid; i < CV; i += 256) {
        int o = i / NV, v = i % NV;
        const float* w0 = Wgcn + o * NC;
        const float* w1 = Wgcn + NC * NC + o * NC;
        const float* w2 = Wgcn + 2 * NC * NC + o * NC;
        const float* w3 = Wadyn + o * NC;
        float a0 = 0.f, a1 = 0.f, a2 = 0.f, a3 = 0.f;
        for (int c = 0; c < NC; ++c) {
            float xv = Xs[c * NV + v];
            a0 = fmaf(w0[c], xv, a0);
            a1 = fmaf(w1[c], xv, a1);
            a2 = fmaf(w2[c], xv, a2);
            a3 = fmaf(w3[c], xv, a3);
        }
        Zs[i] = a0 * (1.f / 3.f);
        Zs[CV + i] = a1 * (1.f / 3.f);
        Zs[2 * CV + i] = a2 * (1.f / 3.f);
        Zs[3 * CV + i] = a3 * sg;
    }
    __syncthreads();
    const float* Adb = Ad + b * NV * NV;
    for (int i = tid; i < CV; i += 256) {
        int o = i / NV, w = i % NV;
        float acc = 0.f;
        for (int v = 0; v < NV; ++v) {
            acc = fmaf(Zs[o * NV + v], Agcn[v * NV + w], acc);
            acc = fmaf(Zs[CV + o * NV + v], Agcn[NV * NV + v * NV + w], acc);
            acc = fmaf(Zs[2 * CV + o * NV + v], Agcn[2 * NV * NV + v * NV + w], acc);
            acc = fmaf(Zs[3 * CV + o * NV + v], Adb[v * NV + w], acc);
        }
        float val = hswish(bnval(acc, gbn, NC, o));
        x3[(((size_t)b * NC + o) * NT + t) * NV + w] = val;
    }
}

// ---- K3a: s[b,c] = mean_{t,v} x3 ----
__global__ __launch_bounds__(256) void k_sred(const float* __restrict__ x3,
                                              float* __restrict__ s) {
    int bc = blockIdx.x, tid = threadIdx.x;
    const float* p = x3 + (size_t)bc * NT * NV;
    float acc = 0.f;
    for (int i = tid; i < NT * NV; i += 256) acc += p[i];
    for (int off = 32; off > 0; off >>= 1) acc += __shfl_down(acc, off, 64);
    __shared__ float part[4];
    if ((tid & 63) == 0) part[tid >> 6] = acc;
    __syncthreads();
    if (tid == 0) s[bc] = (part[0] + part[1] + part[2] + part[3]) / (float)(NT * NV);
}

// ---- K3b: SE MLP -> z[b,c] ----
__global__ __launch_bounds__(128) void k_se(const float* __restrict__ s,
                                            const float* __restrict__ w1,
                                            const float* __restrict__ b1,
                                            const float* __restrict__ w2,
                                            const float* __restrict__ b2,
                                            float* __restrict__ z) {
    int b = blockIdx.x, tid = threadIdx.x;
    __shared__ float sl[NC], hl[NBC];
    if (tid < NC) sl[tid] = s[b * NC + tid];
    __syncthreads();
    if (tid < NBC) {
        float acc = b1[tid];
        for (int c = 0; c < NC; ++c) acc = fmaf(w1[tid * NC + c], sl[c], acc);
        hl[tid] = fmaxf(acc, 0.f);
    }
    __syncthreads();
    if (tid < NC) {
        float acc = b2[tid];
        for (int j = 0; j < NBC; ++j) acc = fmaf(w2[tid * NBC + j], hl[j], acc);
        z[b * NC + tid] = 1.f / (1.f + expf(-acc));
    }
}

// ---- K4: SE-scale + 4x pointwise conv + bn (+hswish for a,b), in-place on x3 ----
__global__ __launch_bounds__(256) void k_pw(float* __restrict__ x3,
                                            const float* __restrict__ z,
                                            const float* __restrict__ pa_w, const float* __restrict__ pa_bn,
                                            const float* __restrict__ pb_w, const float* __restrict__ pb_bn,
                                            const float* __restrict__ pc_w, const float* __restrict__ pc_bn,
                                            const float* __restrict__ pd_w, const float* __restrict__ pd_bn) {
    int t = blockIdx.x % NT, b = blockIdx.x / NT;
    int tid = threadIdx.x;
    __shared__ float xs[CV];
    for (int i = tid; i < CV; i += 256) {
        int c = i / NV;
        xs[i] = x3[(((size_t)b * NC + c) * NT + t) * NV + (i % NV)] * z[b * NC + c];
    }
    __syncthreads();
    for (int i = tid; i < CV; i += 256) {
        int o = i / NV, v = i % NV;
        int br = o / NBC, lc = o % NBC;
        const float* P;
        const float* bnp;
        bool act;
        if (br == 0) { P = pa_w; bnp = pa_bn; act = true; }
        else if (br == 1) { P = pb_w; bnp = pb_bn; act = true; }
        else if (br == 2) { P = pc_w; bnp = pc_bn; act = false; }
        else { P = pd_w; bnp = pd_bn; act = false; }
        float acc = 0.f;
        for (int c = 0; c < NC; ++c) acc = fmaf(P[lc * NC + c], xs[c * NV + v], acc);
        float val = bnval(acc, bnp, NBC, lc);
        if (act) val = hswish(val);
        x3[(((size_t)b * NC + o) * NT + t) * NV + v] = val;
    }
}

// ---- K5: temporal convs / maxpool / identity + residual + hswish -> out ----
__global__ __launch_bounds__(256) void k_tcn(const float* __restrict__ u,
                                             const float* __restrict__ x,
                                             const float* __restrict__ ta_w, const float* __restrict__ ta_bn,
                                             const float* __restrict__ tb_w, const float* __restrict__ tb_bn,
                                             float* __restrict__ out) {
    size_t gid = (size_t)blockIdx.x * 256 + threadIdx.x;
    if (gid >= (size_t)NB * NC * NT * NV) return;
    int v = gid % NV;
    size_t r = gid / NV;
    int t = r % NT; r /= NT;
    int oc = r % NC;
    int b = r / NC;
    int br = oc / NBC, lc = oc % NBC;
    float val;
    if (br == 0) {
        float acc = 0.f;
        for (int i = 0; i < 3; ++i) {
            int tt = t - 1 + i;
            if ((unsigned)tt < (unsigned)NT) {
                const float* up = u + (((size_t)b * NC) * NT + tt) * NV + v;
                for (int c2 = 0; c2 < NBC; ++c2)
                    acc = fmaf(ta_w[(lc * NBC + c2) * 3 + i], up[(size_t)c2 * NT * NV], acc);
            }
        }
        val = bnval(acc, ta_bn, NBC, lc);
    } else if (br == 1) {
        float acc = 0.f;
        for (int i = 0; i < 3; ++i) {
            int tt = t - 2 + 2 * i;
            if ((unsigned)tt < (unsigned)NT) {
                const float* up = u + (((size_t)b * NC + NBC) * NT + tt) * NV + v;
                for (int c2 = 0; c2 < NBC; ++c2)
                    acc = fmaf(tb_w[(lc * NBC + c2) * 3 + i], up[(size_t)c2 * NT * NV], acc);
            }
        }
        val = bnval(acc, tb_bn, NBC, lc);
    } else if (br == 2) {
        float m = -INFINITY;
        for (int dt = -1; dt <= 1; ++dt) {
            int tt = t + dt;
            if ((unsigned)tt < (unsigned)NT)
                m = fmaxf(m, u[(((size_t)b * NC + 2 * NBC + lc) * NT + tt) * NV + v]);
        }
        val = m;
    } else {
        val = u[(((size_t)b * NC + 3 * NBC + lc) * NT + t) * NV + v];
    }
    float sres = val + x[gid];
    out[gid] = hswish(sres);
}

extern "C" void kernel_launch(void* const* d_in, const int* in_sizes, int n_in,
                              void* d_out, int out_size, void* d_ws, size_t ws_size,
                              hipStream_t stream) {
    const float* x = (const float*)d_in[0];
    const int* intra = (const int*)d_in[1];
    const int* inter = (const int*)d_in[2];
    const float* A_gcn = (const float*)d_in[3];
    const float* W_gcn = (const float*)d_in[4];
    const float* gcn_bn = (const float*)d_in[5];
    const float* Wp = (const float*)d_in[6];
    const float* W_adyn = (const float*)d_in[7];
    const float* gate = (const float*)d_in[8];
    const float* se_w1 = (const float*)d_in[9];
    const float* se_b1 = (const float*)d_in[10];
    const float* se_w2 = (const float*)d_in[11];
    const float* se_b2 = (const float*)d_in[12];
    const float* pa_w = (const float*)d_in[13];
    const float* pa_bn = (const float*)d_in[14];
    const float* ta_w = (const float*)d_in[15];
    const float* ta_bn = (const float*)d_in[16];
    const float* pb_w = (const float*)d_in[17];
    const float* pb_bn = (const float*)d_in[18];
    const float* tb_w = (const float*)d_in[19];
    const float* tb_bn = (const float*)d_in[20];
    const float* pc_w = (const float*)d_in[21];
    const float* pc_bn = (const float*)d_in[22];
    const float* pd_w = (const float*)d_in[23];
    const float* pd_bn = (const float*)d_in[24];
    float* out = (float*)d_out;

    // workspace layout (floats)
    float* ws = (float*)d_ws;
    float* x3 = ws;                                   // B*C*T*V = 19,660,800
    float* xm = x3 + (size_t)NB * NC * NT * NV;       // B*C*V   = 76,800
    float* Ad = xm + NB * NC * NV;                    // B*V*V   = 20,000
    float* sb = Ad + NB * NV * NV;                    // B*C     = 3,072
    float* zb = sb + NB * NC;                         // B*C     = 3,072

    k_mean<<<NB * NC, 256, 0, stream>>>(x, xm);
    k_adyn<<<NB, 256, 0, stream>>>(xm, Wp, intra, inter, Ad);
    k_gcn<<<NB * NT, 256, 0, stream>>>(x, intra, inter, A_gcn, W_gcn, W_adyn,
                                       gate, gcn_bn, Ad, x3);
    k_sred<<<NB * NC, 256, 0, stream>>>(x3, sb);
    k_se<<<NB, 128, 0, stream>>>(sb, se_w1, se_b1, se_w2, se_b2, zb);
    k_pw<<<NB * NT, 256, 0, stream>>>(x3, zb, pa_w, pa_bn, pb_w, pb_bn,
                                      pc_w, pc_bn, pd_w, pd_bn);
    int total = NB * NC * NT * NV;
    k_tcn<<<(total + 255) / 256, 256, 0, stream>>>(x3, x, ta_w, ta_bn, tb_w, tb_bn, out);
}

// Round 2
// 703.376 us; speedup vs baseline: 2.9248x; 2.9248x over previous
//
#include <hip/hip_runtime.h>
#include <math.h>

#define NB 32
#define NC 96
#define NT 256
#define NV 25
#define NBC 24
#define NE 24
#define CV (NC * NV)          // 2400
#define EV (NE * NV)          // 600
#define NK4 384               // 4*NC  (stage-B K)
#define NN 6400               // NT*NV (stage-B N per batch)
#define ACOLS 112             // padded (j,w) columns (100 -> 112)
#define APAD 40               // padded K stride in shorts (32 -> 40, conflict-free)

typedef __attribute__((ext_vector_type(8))) short bf16x8;
typedef __attribute__((ext_vector_type(4))) float f32x4;

__device__ __forceinline__ float hswish(float x) {
    return x * fminf(fmaxf(x + 3.f, 0.f), 6.f) * (1.f / 6.f);
}
__device__ __forceinline__ float bnval(float x, const float* p, int n, int c) {
    // p layout [4][n]: gamma, beta, rm, rv
    return (x - p[2 * n + c]) * p[c] * rsqrtf(p[3 * n + c] + 1e-5f) + p[n + c];
}
__device__ __forceinline__ unsigned short f2bf(float f) {
    unsigned u = __float_as_uint(f);
    u += 0x7fffu + ((u >> 16) & 1u);   // RNE
    return (unsigned short)(u >> 16);
}

// ---- K1a: xmean[b,c,v] = mean_t x[b,c,t,v] ----
__global__ __launch_bounds__(256) void k_mean(const float* __restrict__ x,
                                              float* __restrict__ xm) {
    int bc = blockIdx.x;
    int tid = threadIdx.x;
    const float* xp = x + (size_t)bc * NT * NV + (size_t)tid * NV;
    float a[NV];
#pragma unroll
    for (int v = 0; v < NV; ++v) a[v] = xp[v];
    __shared__ float part[4][NV];
    int lane = tid & 63, wid = tid >> 6;
#pragma unroll
    for (int v = 0; v < NV; ++v) {
        float val = a[v];
        for (int off = 32; off > 0; off >>= 1) val += __shfl_down(val, off, 64);
        if (lane == 0) part[wid][v] = val;
    }
    __syncthreads();
    if (tid < NV) {
        float s = part[0][tid] + part[1][tid] + part[2][tid] + part[3][tid];
        xm[bc * NV + tid] = s * (1.0f / NT);
    }
}

// ---- K1b: dynamic adjacency -> fused Acat^T (bf16, padded) ----
// acat[b][col=(j,w) 0..111][v 0..39]; j<3: A_j[v,w]/3 ; j==3: sg*A_dyn[v,w]
__global__ __launch_bounds__(256) void k_adyn(const float* __restrict__ xm,
                                              const float* __restrict__ Wp,
                                              const int* __restrict__ intra,
                                              const int* __restrict__ inter,
                                              const float* __restrict__ Agcn,
                                              const float* __restrict__ gate,
                                              unsigned short* __restrict__ acat) {
    int b = blockIdx.x, tid = threadIdx.x;
    __shared__ float xms[CV];
    __shared__ float embs[EV];
    __shared__ float nrm[NV];
    __shared__ float Ads[NV * NV];
    for (int i = tid; i < CV; i += 256) xms[i] = xm[b * CV + i];
    __syncthreads();
    for (int i = tid; i < EV; i += 256) {
        int e = i / NV, v = i % NV;
        int iv = intra[v], ev2 = inter[v];
        float acc = 0.f;
        for (int c = 0; c < NC; ++c) {
            int s0 = (c < NC / 2) ? iv : ev2;
            int col = (s0 + c) % NV;
            acc = fmaf(xms[c * NV + col], Wp[e * NC + c], acc);
        }
        embs[e * NV + v] = acc;
    }
    __syncthreads();
    if (tid < NV) {
        float acc = 0.f;
        for (int e = 0; e < NE; ++e) {
            float t = embs[e * NV + tid];
            acc = fmaf(t, t, acc);
        }
        nrm[tid] = sqrtf(acc) + 1e-12f;
    }
    __syncthreads();
    for (int i = tid; i < NV * NV; i += 256) {
        int v = i / NV, w = i % NV;
        float acc = 0.f;
        for (int e = 0; e < NE; ++e)
            acc = fmaf(embs[e * NV + v], embs[e * NV + w], acc);
        Ads[i] = acc / (nrm[v] * nrm[w]);
    }
    __syncthreads();
    float sg = 1.f / (1.f + expf(-gate[0]));
    for (int i = tid; i < ACOLS * APAD; i += 256) {
        int col = i / APAD, v = i % APAD;
        float val = 0.f;
        if (col < 100 && v < NV) {
            int j = col / NV, w = col % NV;
            if (j < 3) val = Agcn[(j * NV + v) * NV + w] * (1.f / 3.f);
            else val = sg * Ads[v * NV + w];
        }
        acat[(size_t)b * ACOLS * APAD + i] = f2bf(val);
    }
}

// ---- K1c: Wcat bf16 [o=96][kc=(j,c) 384] ----
__global__ __launch_bounds__(256) void k_wcat(const float* __restrict__ Wg,
                                              const float* __restrict__ Wa,
                                              unsigned short* __restrict__ wcat) {
    int i = blockIdx.x * 256 + threadIdx.x;
    if (i >= NC * NK4) return;
    int o = i / NK4, kc = i % NK4;
    int j = kc / NC, c = kc % NC;
    float v = (j < 3) ? Wg[(j * NC + o) * NC + c] : Wa[o * NC + c];
    wcat[i] = f2bf(v);
}

// ---- K2a: Xa[(j,c),(t,w)] = X_sh[(c,t),v] @ AcatT  (MFMA, per-b rows chunked) ----
__global__ __launch_bounds__(256) void k_xa(const float* __restrict__ x,
                                            const int* __restrict__ intra,
                                            const int* __restrict__ inter,
                                            const unsigned short* __restrict__ acat,
                                            unsigned short* __restrict__ xa, int b0) {
    int blk = blockIdx.x;
    int b = b0 + blk / 384;
    int r0 = (blk % 384) * 64;      // 64 rows of (c,t), r = c*256 + t
    int tid = threadIdx.x;
    __shared__ __align__(16) unsigned short Xs[64][APAD];
    __shared__ __align__(16) unsigned short Bs[ACOLS][APAD];
    {   // copy AcatT panel (already padded/packed)
        const bf16x8* src = (const bf16x8*)(acat + (size_t)b * ACOLS * APAD);
        bf16x8* dst = (bf16x8*)&Bs[0][0];
        for (int i = tid; i < ACOLS * APAD / 8; i += 256) dst[i] = src[i];
    }
    for (int i = tid; i < 64 * APAD; i += 256) {
        int row = i / APAD, v = i % APAD;
        unsigned short val = 0;
        if (v < NV) {
            int r = r0 + row;
            int c = r >> 8, t = r & 255;
            int s0 = (c < NC / 2) ? intra[v] : inter[v];
            int col = (s0 + c) % NV;
            val = f2bf(x[(((size_t)b * NC + c) * NT + t) * NV + col]);
        }
        Xs[row][v] = val;
    }
    __syncthreads();
    int lane = tid & 63, wv = tid >> 6;
    int lr = lane & 15, kg = lane >> 4;
    bf16x8 a = *(const bf16x8*)&Xs[wv * 16 + lr][kg * 8];
    f32x4 acc[7];
#pragma unroll
    for (int nt = 0; nt < 7; ++nt) {
        f32x4 z = {0.f, 0.f, 0.f, 0.f};
        bf16x8 bb = *(const bf16x8*)&Bs[nt * 16 + lr][kg * 8];
        acc[nt] = __builtin_amdgcn_mfma_f32_16x16x32_bf16(a, bb, z, 0, 0, 0);
    }
#pragma unroll
    for (int nt = 0; nt < 7; ++nt) {
        int colbase = nt * 16 + lr;
        if (colbase < 100) {
            int j = colbase / NV, w = colbase % NV;
#pragma unroll
            for (int i = 0; i < 4; ++i) {
                int r = r0 + wv * 16 + kg * 4 + i;
                int c = r >> 8, t = r & 255;
                xa[((size_t)b * NK4 + j * NC + c) * NN + t * NV + w] = f2bf(acc[nt][i]);
            }
        }
    }
}

// ---- K2b: x3 = hswish(bn(Wcat @ Xa))  (MFMA GEMM M=96,K=384,N=6400 per b) ----
__global__ __launch_bounds__(256) void k_gemm(const unsigned short* __restrict__ xa,
                                              const unsigned short* __restrict__ wcat,
                                              const float* __restrict__ gbn,
                                              float* __restrict__ x3, int b0) {
    int blk = blockIdx.x;
    int b = b0 + blk / 50;
    int n0 = (blk % 50) * 128;
    int tid = threadIdx.x;
    __shared__ __align__(16) unsigned short Wpan[NC][APAD];
    __shared__ __align__(16) unsigned short Xp[128][APAD];
    int lane = tid & 63, wv = tid >> 6;
    int lr = lane & 15, kg = lane >> 4;
    f32x4 acc[6][2];
#pragma unroll
    for (int mt = 0; mt < 6; ++mt)
#pragma unroll
        for (int nn = 0; nn < 2; ++nn) acc[mt][nn] = (f32x4){0.f, 0.f, 0.f, 0.f};

    int kp = tid >> 4;    // 0..15: handles k rows 2kp, 2kp+1
    int seg = tid & 15;   // 0..15: 8-col segment

    for (int kt = 0; kt < 12; ++kt) {
        int k0 = kt * 32;
        for (int i = tid; i < 384; i += 256) {          // W panel [96][32]
            int o = i >> 2, s4 = i & 3;
            *(bf16x8*)&Wpan[o][s4 * 8] = *(const bf16x8*)(wcat + o * NK4 + k0 + s4 * 8);
        }
        {   // Xa panel transposed -> Xp[n][k], XOR-granule swizzled
            const unsigned short* src0 = xa + ((size_t)b * NK4 + k0 + 2 * kp) * NN + n0 + seg * 8;
            bf16x8 va = *(const bf16x8*)src0;
            bf16x8 vb = *(const bf16x8*)(src0 + NN);
            char* base = (char*)&Xp[0][0];
#pragma unroll
            for (int e = 0; e < 8; ++e) {
                int n = seg * 8 + e;
                int g = (kp >> 2) ^ (n & 3) ^ ((n >> 3) & 3);
                unsigned pk = (unsigned)(unsigned short)va[e] |
                              ((unsigned)(unsigned short)vb[e] << 16);
                *(unsigned*)(base + n * 80 + g * 16 + (kp & 3) * 4) = pk;
            }
        }
        __syncthreads();
        bf16x8 afr[6];
#pragma unroll
        for (int mt = 0; mt < 6; ++mt)
            afr[mt] = *(const bf16x8*)&Wpan[mt * 16 + lr][kg * 8];
#pragma unroll
        for (int nn = 0; nn < 2; ++nn) {
            int nl = (wv * 2 + nn) * 16 + lr;
            int g = kg ^ (nl & 3) ^ ((nl >> 3) & 3);
            bf16x8 bb = *(const bf16x8*)((const char*)&Xp[0][0] + nl * 80 + g * 16);
#pragma unroll
            for (int mt = 0; mt < 6; ++mt)
                acc[mt][nn] = __builtin_amdgcn_mfma_f32_16x16x32_bf16(afr[mt], bb, acc[mt][nn], 0, 0, 0);
        }
        __syncthreads();
    }
#pragma unroll
    for (int mt = 0; mt < 6; ++mt)
#pragma unroll
        for (int nn = 0; nn < 2; ++nn) {
            int n = n0 + (wv * 2 + nn) * 16 + lr;
#pragma unroll
            for (int i = 0; i < 4; ++i) {
                int o = mt * 16 + kg * 4 + i;
                float val = acc[mt][nn][i];
                val = hswish(bnval(val, gbn, NC, o));
                x3[((size_t)b * NC + o) * NN + n] = val;
            }
        }
}

// ---- K3a: s[b,c] = mean_{t,v} x3 ----
__global__ __launch_bounds__(256) void k_sred(const float* __restrict__ x3,
                                              float* __restrict__ s) {
    int bc = blockIdx.x, tid = threadIdx.x;
    const float* p = x3 + (size_t)bc * NT * NV;
    float acc = 0.f;
    for (int i = tid; i < NT * NV; i += 256) acc += p[i];
    for (int off = 32; off > 0; off >>= 1) acc += __shfl_down(acc, off, 64);
    __shared__ float part[4];
    if ((tid & 63) == 0) part[tid >> 6] = acc;
    __syncthreads();
    if (tid == 0) s[bc] = (part[0] + part[1] + part[2] + part[3]) / (float)(NT * NV);
}

// ---- K3b: SE MLP -> z[b,c] ----
__global__ __launch_bounds__(128) void k_se(const float* __restrict__ s,
                                            const float* __restrict__ w1,
                                            const float* __restrict__ b1,
                                            const float* __restrict__ w2,
                                            const float* __restrict__ b2,
                                            float* __restrict__ z) {
    int b = blockIdx.x, tid = threadIdx.x;
    __shared__ float sl[NC], hl[NBC];
    if (tid < NC) sl[tid] = s[b * NC + tid];
    __syncthreads();
    if (tid < NBC) {
        float acc = b1[tid];
        for (int c = 0; c < NC; ++c) acc = fmaf(w1[tid * NC + c], sl[c], acc);
        hl[tid] = fmaxf(acc, 0.f);
    }
    __syncthreads();
    if (tid < NC) {
        float acc = b2[tid];
        for (int j = 0; j < NBC; ++j) acc = fmaf(w2[tid * NBC + j], hl[j], acc);
        z[b * NC + tid] = 1.f / (1.f + expf(-acc));
    }
}

// ---- K4: SE-scale + 4x pointwise conv + bn (+hswish for a,b), in-place on x3 ----
__global__ __launch_bounds__(256) void k_pw(float* __restrict__ x3,
                                            const float* __restrict__ z,
                                            const float* __restrict__ pa_w, const float* __restrict__ pa_bn,
                                            const float* __restrict__ pb_w, const float* __restrict__ pb_bn,
                                            const float* __restrict__ pc_w, const float* __restrict__ pc_bn,
                                            const float* __restrict__ pd_w, const float* __restrict__ pd_bn) {
    int t = blockIdx.x % NT, b = blockIdx.x / NT;
    int tid = threadIdx.x;
    __shared__ float xs[CV];
    for (int i = tid; i < CV; i += 256) {
        int c = i / NV;
        xs[i] = x3[(((size_t)b * NC + c) * NT + t) * NV + (i % NV)] * z[b * NC + c];
    }
    __syncthreads();
    for (int i = tid; i < CV; i += 256) {
        int o = i / NV, v = i % NV;
        int br = o / NBC, lc = o % NBC;
        const float* P;
        const float* bnp;
        bool act;
        if (br == 0) { P = pa_w; bnp = pa_bn; act = true; }
        else if (br == 1) { P = pb_w; bnp = pb_bn; act = true; }
        else if (br == 2) { P = pc_w; bnp = pc_bn; act = false; }
        else { P = pd_w; bnp = pd_bn; act = false; }
        float acc = 0.f;
        for (int c = 0; c < NC; ++c) acc = fmaf(P[lc * NC + c], xs[c * NV + v], acc);
        float val = bnval(acc, bnp, NBC, lc);
        if (act) val = hswish(val);
        x3[(((size_t)b * NC + o) * NT + t) * NV + v] = val;
    }
}

// ---- K5: temporal convs / maxpool / identity + residual + hswish -> out ----
__global__ __launch_bounds__(256) void k_tcn(const float* __restrict__ u,
                                             const float* __restrict__ x,
                                             const float* __restrict__ ta_w, const float* __restrict__ ta_bn,
                                             const float* __restrict__ tb_w, const float* __restrict__ tb_bn,
                                             float* __restrict__ out) {
    size_t gid = (size_t)blockIdx.x * 256 + threadIdx.x;
    if (gid >= (size_t)NB * NC * NT * NV) return;
    int v = gid % NV;
    size_t r = gid / NV;
    int t = r % NT; r /= NT;
    int oc = r % NC;
    int b = r / NC;
    int br = oc / NBC, lc = oc % NBC;
    float val;
    if (br == 0) {
        float acc = 0.f;
        for (int i = 0; i < 3; ++i) {
            int tt = t - 1 + i;
            if ((unsigned)tt < (unsigned)NT) {
                const float* up = u + (((size_t)b * NC) * NT + tt) * NV + v;
                for (int c2 = 0; c2 < NBC; ++c2)
                    acc = fmaf(ta_w[(lc * NBC + c2) * 3 + i], up[(size_t)c2 * NT * NV], acc);
            }
        }
        val = bnval(acc, ta_bn, NBC, lc);
    } else if (br == 1) {
        float acc = 0.f;
        for (int i = 0; i < 3; ++i) {
            int tt = t - 2 + 2 * i;
            if ((unsigned)tt < (unsigned)NT) {
                const float* up = u + (((size_t)b * NC + NBC) * NT + tt) * NV + v;
                for (int c2 = 0; c2 < NBC; ++c2)
                    acc = fmaf(tb_w[(lc * NBC + c2) * 3 + i], up[(size_t)c2 * NT * NV], acc);
            }
        }
        val = bnval(acc, tb_bn, NBC, lc);
    } else if (br == 2) {
        float m = -INFINITY;
        for (int dt = -1; dt <= 1; ++dt) {
            int tt = t + dt;
            if ((unsigned)tt < (unsigned)NT)
                m = fmaxf(m, u[(((size_t)b * NC + 2 * NBC + lc) * NT + tt) * NV + v]);
        }
        val = m;
    } else {
        val = u[(((size_t)b * NC + 3 * NBC + lc) * NT + t) * NV + v];
    }
    float sres = val + x[gid];
    out[gid] = hswish(sres);
}

extern "C" void kernel_launch(void* const* d_in, const int* in_sizes, int n_in,
                              void* d_out, int out_size, void* d_ws, size_t ws_size,
                              hipStream_t stream) {
    const float* x = (const float*)d_in[0];
    const int* intra = (const int*)d_in[1];
    const int* inter = (const int*)d_in[2];
    const float* A_gcn = (const float*)d_in[3];
    const float* W_gcn = (const float*)d_in[4];
    const float* gcn_bn = (const float*)d_in[5];
    const float* Wp = (const float*)d_in[6];
    const float* W_adyn = (const float*)d_in[7];
    const float* gate = (const float*)d_in[8];
    const float* se_w1 = (const float*)d_in[9];
    const float* se_b1 = (const float*)d_in[10];
    const float* se_w2 = (const float*)d_in[11];
    const float* se_b2 = (const float*)d_in[12];
    const float* pa_w = (const float*)d_in[13];
    const float* pa_bn = (const float*)d_in[14];
    const float* ta_w = (const float*)d_in[15];
    const float* ta_bn = (const float*)d_in[16];
    const float* pb_w = (const float*)d_in[17];
    const float* pb_bn = (const float*)d_in[18];
    const float* tb_w = (const float*)d_in[19];
    const float* tb_bn = (const float*)d_in[20];
    const float* pc_w = (const float*)d_in[21];
    const float* pc_bn = (const float*)d_in[22];
    const float* pd_w = (const float*)d_in[23];
    const float* pd_bn = (const float*)d_in[24];
    float* out = (float*)d_out;

    // workspace layout (float slots, every slice 16B-aligned)
    float* ws = (float*)d_ws;
    float* x3 = ws;                                        // 19,660,800 f
    float* xm = x3 + (size_t)NB * NC * NT * NV;            // 76,800 f
    float* sb = xm + NB * NC * NV;                         // 3,072 f
    float* zb = sb + NB * NC;                              // 3,072 f
    unsigned short* wcat = (unsigned short*)(zb + NB * NC);        // 36,864 us (18,432 f)
    unsigned short* acat = wcat + NC * NK4;                        // 143,360 us (71,680 f)
    unsigned short* xabuf = acat + NB * ACOLS * APAD;              // chunk*2,457,600 us
    size_t base_f = (size_t)NB * NC * NT * NV + NB * NC * NV + 2 * NB * NC
                  + (NC * NK4) / 2 + (NB * ACOLS * APAD) / 2;

    int chunk = 1;
    const int cands[6] = {32, 16, 8, 4, 2, 1};
    for (int ci = 0; ci < 6; ++ci) {
        size_t need = (base_f + (size_t)cands[ci] * NK4 * NN / 2) * 4;
        if (need <= ws_size) { chunk = cands[ci]; break; }
    }

    k_mean<<<NB * NC, 256, 0, stream>>>(x, xm);
    k_adyn<<<NB, 256, 0, stream>>>(xm, Wp, intra, inter, A_gcn, gate, acat);
    k_wcat<<<(NC * NK4 + 255) / 256, 256, 0, stream>>>(W_gcn, W_adyn, wcat);
    for (int b0 = 0; b0 < NB; b0 += chunk) {
        k_xa<<<chunk * 384, 256, 0, stream>>>(x, intra, inter, acat, xabuf, b0);
        k_gemm<<<chunk * 50, 256, 0, stream>>>(xabuf, wcat, gcn_bn, x3, b0);
    }
    k_sred<<<NB * NC, 256, 0, stream>>>(x3, sb);
    k_se<<<NB, 128, 0, stream>>>(sb, se_w1, se_b1, se_w2, se_b2, zb);
    k_pw<<<NB * NT, 256, 0, stream>>>(x3, zb, pa_w, pa_bn, pb_w, pb_bn,
                                      pc_w, pc_bn, pd_w, pd_bn);
    int total = NB * NC * NT * NV;
    k_tcn<<<(total + 255) / 256, 256, 0, stream>>>(x3, x, ta_w, ta_bn, tb_w, tb_bn, out);
}

// Round 3
// 450.659 us; speedup vs baseline: 4.5650x; 1.5608x over previous
//
#include <hip/hip_runtime.h>
#include <math.h>

#define NB 32
#define NC 96
#define NT 256
#define NV 25
#define NBC 24
#define NE 24
#define CV (NC * NV)          // 2400
#define EV (NE * NV)          // 600
#define NK4 384               // 4*NC  (stage-B K)
#define NN 6400               // NT*NV (stage-B N per batch)
#define ACOLS 112             // padded (j,w) columns (100 -> 112)
#define APAD 40               // padded K stride in shorts (32 -> 40, conflict-free)

typedef __attribute__((ext_vector_type(8))) short bf16x8;
typedef __attribute__((ext_vector_type(4))) float f32x4;

__device__ __forceinline__ float hswish(float x) {
    return x * fminf(fmaxf(x + 3.f, 0.f), 6.f) * (1.f / 6.f);
}
__device__ __forceinline__ float bnval(float x, const float* p, int n, int c) {
    // p layout [4][n]: gamma, beta, rm, rv
    return (x - p[2 * n + c]) * p[c] * rsqrtf(p[3 * n + c] + 1e-5f) + p[n + c];
}
__device__ __forceinline__ unsigned short f2bf(float f) {
    unsigned u = __float_as_uint(f);
    u += 0x7fffu + ((u >> 16) & 1u);   // RNE
    return (unsigned short)(u >> 16);
}
__device__ __forceinline__ float bf2f(unsigned short us) {
    return __uint_as_float((unsigned)us << 16);
}

// ---- K1a: xmean[b,c,v] = mean_t x[b,c,t,v] ----
__global__ __launch_bounds__(256) void k_mean(const float* __restrict__ x,
                                              float* __restrict__ xm) {
    int bc = blockIdx.x;
    int tid = threadIdx.x;
    const float* xp = x + (size_t)bc * NT * NV + (size_t)tid * NV;
    float a[NV];
#pragma unroll
    for (int v = 0; v < NV; ++v) a[v] = xp[v];
    __shared__ float part[4][NV];
    int lane = tid & 63, wid = tid >> 6;
#pragma unroll
    for (int v = 0; v < NV; ++v) {
        float val = a[v];
        for (int off = 32; off > 0; off >>= 1) val += __shfl_down(val, off, 64);
        if (lane == 0) part[wid][v] = val;
    }
    __syncthreads();
    if (tid < NV) {
        float s = part[0][tid] + part[1][tid] + part[2][tid] + part[3][tid];
        xm[bc * NV + tid] = s * (1.0f / NT);
    }
}

// ---- K1b: dynamic adjacency -> fused Acat^T (bf16, padded) ----
__global__ __launch_bounds__(256) void k_adyn(const float* __restrict__ xm,
                                              const float* __restrict__ Wp,
                                              const int* __restrict__ intra,
                                              const int* __restrict__ inter,
                                              const float* __restrict__ Agcn,
                                              const float* __restrict__ gate,
                                              unsigned short* __restrict__ acat) {
    int b = blockIdx.x, tid = threadIdx.x;
    __shared__ float xms[CV];
    __shared__ float embs[EV];
    __shared__ float nrm[NV];
    __shared__ float Ads[NV * NV];
    for (int i = tid; i < CV; i += 256) xms[i] = xm[b * CV + i];
    __syncthreads();
    for (int i = tid; i < EV; i += 256) {
        int e = i / NV, v = i % NV;
        int iv = intra[v], ev2 = inter[v];
        float acc = 0.f;
        for (int c = 0; c < NC; ++c) {
            int s0 = (c < NC / 2) ? iv : ev2;
            int col = (s0 + c) % NV;
            acc = fmaf(xms[c * NV + col], Wp[e * NC + c], acc);
        }
        embs[e * NV + v] = acc;
    }
    __syncthreads();
    if (tid < NV) {
        float acc = 0.f;
        for (int e = 0; e < NE; ++e) {
            float t = embs[e * NV + tid];
            acc = fmaf(t, t, acc);
        }
        nrm[tid] = sqrtf(acc) + 1e-12f;
    }
    __syncthreads();
    for (int i = tid; i < NV * NV; i += 256) {
        int v = i / NV, w = i % NV;
        float acc = 0.f;
        for (int e = 0; e < NE; ++e)
            acc = fmaf(embs[e * NV + v], embs[e * NV + w], acc);
        Ads[i] = acc / (nrm[v] * nrm[w]);
    }
    __syncthreads();
    float sg = 1.f / (1.f + expf(-gate[0]));
    for (int i = tid; i < ACOLS * APAD; i += 256) {
        int col = i / APAD, v = i % APAD;
        float val = 0.f;
        if (col < 100 && v < NV) {
            int j = col / NV, w = col % NV;
            if (j < 3) val = Agcn[(j * NV + v) * NV + w] * (1.f / 3.f);
            else val = sg * Ads[v * NV + w];
        }
        acat[(size_t)b * ACOLS * APAD + i] = f2bf(val);
    }
}

// ---- K1c: Wcat bf16 [o=96][kc=(j,c) 384] ----
__global__ __launch_bounds__(256) void k_wcat(const float* __restrict__ Wg,
                                              const float* __restrict__ Wa,
                                              unsigned short* __restrict__ wcat) {
    int i = blockIdx.x * 256 + threadIdx.x;
    if (i >= NC * NK4) return;
    int o = i / NK4, kc = i % NK4;
    int j = kc / NC, c = kc % NC;
    float v = (j < 3) ? Wg[(j * NC + o) * NC + c] : Wa[o * NC + c];
    wcat[i] = f2bf(v);
}

// ---- K2a: Xa[(j,c),(t,w)] = X_sh[(c,t),v] @ AcatT  (MFMA) ----
__global__ __launch_bounds__(256) void k_xa(const float* __restrict__ x,
                                            const int* __restrict__ intra,
                                            const int* __restrict__ inter,
                                            const unsigned short* __restrict__ acat,
                                            unsigned short* __restrict__ xa, int b0) {
    int blk = blockIdx.x;
    int b = b0 + blk / 384;
    int r0 = (blk % 384) * 64;      // 64 rows of (c,t), r = c*256 + t
    int tid = threadIdx.x;
    __shared__ __align__(16) unsigned short Xs[64][APAD];
    __shared__ __align__(16) unsigned short Bs[ACOLS][APAD];
    {
        const bf16x8* src = (const bf16x8*)(acat + (size_t)b * ACOLS * APAD);
        bf16x8* dst = (bf16x8*)&Bs[0][0];
        for (int i = tid; i < ACOLS * APAD / 8; i += 256) dst[i] = src[i];
    }
    for (int i = tid; i < 64 * APAD; i += 256) {
        int row = i / APAD, v = i % APAD;
        unsigned short val = 0;
        if (v < NV) {
            int r = r0 + row;
            int c = r >> 8, t = r & 255;
            int s0 = (c < NC / 2) ? intra[v] : inter[v];
            int col = (s0 + c) % NV;
            val = f2bf(x[(((size_t)b * NC + c) * NT + t) * NV + col]);
        }
        Xs[row][v] = val;
    }
    __syncthreads();
    int lane = tid & 63, wv = tid >> 6;
    int lr = lane & 15, kg = lane >> 4;
    bf16x8 a = *(const bf16x8*)&Xs[wv * 16 + lr][kg * 8];
    f32x4 acc[7];
#pragma unroll
    for (int nt = 0; nt < 7; ++nt) {
        f32x4 z = {0.f, 0.f, 0.f, 0.f};
        bf16x8 bb = *(const bf16x8*)&Bs[nt * 16 + lr][kg * 8];
        acc[nt] = __builtin_amdgcn_mfma_f32_16x16x32_bf16(a, bb, z, 0, 0, 0);
    }
#pragma unroll
    for (int nt = 0; nt < 7; ++nt) {
        int colbase = nt * 16 + lr;
        if (colbase < 100) {
            int j = colbase / NV, w = colbase % NV;
#pragma unroll
            for (int i = 0; i < 4; ++i) {
                int r = r0 + wv * 16 + kg * 4 + i;
                int c = r >> 8, t = r & 255;
                xa[((size_t)b * NK4 + j * NC + c) * NN + t * NV + w] = f2bf(acc[nt][i]);
            }
        }
    }
}

// ---- K2b: x3(bf16) = hswish(bn(Wcat @ Xa)) ----
__global__ __launch_bounds__(256) void k_gemm(const unsigned short* __restrict__ xa,
                                              const unsigned short* __restrict__ wcat,
                                              const float* __restrict__ gbn,
                                              unsigned short* __restrict__ x3, int b0) {
    int blk = blockIdx.x;
    int b = b0 + blk / 50;
    int n0 = (blk % 50) * 128;
    int tid = threadIdx.x;
    __shared__ __align__(16) unsigned short Wpan[NC][APAD];
    __shared__ __align__(16) unsigned short Xp[128 * APAD];
    int lane = tid & 63, wv = tid >> 6;
    int lr = lane & 15, kg = lane >> 4;
    f32x4 acc[6][2];
#pragma unroll
    for (int mt = 0; mt < 6; ++mt)
#pragma unroll
        for (int nn = 0; nn < 2; ++nn) acc[mt][nn] = (f32x4){0.f, 0.f, 0.f, 0.f};

    int kp = tid >> 4;
    int seg = tid & 15;

    for (int kt = 0; kt < 12; ++kt) {
        int k0 = kt * 32;
        for (int i = tid; i < 384; i += 256) {
            int o = i >> 2, s4 = i & 3;
            *(bf16x8*)&Wpan[o][s4 * 8] = *(const bf16x8*)(wcat + o * NK4 + k0 + s4 * 8);
        }
        {
            const unsigned short* src0 = xa + ((size_t)b * NK4 + k0 + 2 * kp) * NN + n0 + seg * 8;
            bf16x8 va = *(const bf16x8*)src0;
            bf16x8 vb = *(const bf16x8*)(src0 + NN);
            char* base = (char*)&Xp[0];
#pragma unroll
            for (int e = 0; e < 8; ++e) {
                int n = seg * 8 + e;
                int g = (kp >> 2) ^ (n & 3) ^ ((n >> 3) & 3);
                unsigned pk = (unsigned)(unsigned short)va[e] |
                              ((unsigned)(unsigned short)vb[e] << 16);
                *(unsigned*)(base + n * 80 + g * 16 + (kp & 3) * 4) = pk;
            }
        }
        __syncthreads();
        bf16x8 afr[6];
#pragma unroll
        for (int mt = 0; mt < 6; ++mt)
            afr[mt] = *(const bf16x8*)&Wpan[mt * 16 + lr][kg * 8];
#pragma unroll
        for (int nn = 0; nn < 2; ++nn) {
            int nl = (wv * 2 + nn) * 16 + lr;
            int g = kg ^ (nl & 3) ^ ((nl >> 3) & 3);
            bf16x8 bb = *(const bf16x8*)((const char*)&Xp[0] + nl * 80 + g * 16);
#pragma unroll
            for (int mt = 0; mt < 6; ++mt)
                acc[mt][nn] = __builtin_amdgcn_mfma_f32_16x16x32_bf16(afr[mt], bb, acc[mt][nn], 0, 0, 0);
        }
        __syncthreads();
    }
#pragma unroll
    for (int mt = 0; mt < 6; ++mt)
#pragma unroll
        for (int nn = 0; nn < 2; ++nn) {
            int n = n0 + (wv * 2 + nn) * 16 + lr;
#pragma unroll
            for (int i = 0; i < 4; ++i) {
                int o = mt * 16 + kg * 4 + i;
                float val = acc[mt][nn][i];
                val = hswish(bnval(val, gbn, NC, o));
                x3[((size_t)b * NC + o) * NN + n] = f2bf(val);
            }
        }
}

// ---- K3a: s[b,c] = mean_{t,v} x3 (bf16 in) ----
__global__ __launch_bounds__(256) void k_sred(const unsigned short* __restrict__ x3,
                                              float* __restrict__ s) {
    int bc = blockIdx.x, tid = threadIdx.x;
    const unsigned short* p = x3 + (size_t)bc * NT * NV;
    float acc = 0.f;
    for (int i = tid; i < NN / 8; i += 256) {
        bf16x8 v = *(const bf16x8*)(p + i * 8);
#pragma unroll
        for (int e = 0; e < 8; ++e) acc += bf2f((unsigned short)v[e]);
    }
    for (int off = 32; off > 0; off >>= 1) acc += __shfl_down(acc, off, 64);
    __shared__ float part[4];
    if ((tid & 63) == 0) part[tid >> 6] = acc;
    __syncthreads();
    if (tid == 0) s[bc] = (part[0] + part[1] + part[2] + part[3]) / (float)(NT * NV);
}

// ---- K3b: SE MLP -> z[b,c] ----
__global__ __launch_bounds__(128) void k_se(const float* __restrict__ s,
                                            const float* __restrict__ w1,
                                            const float* __restrict__ b1,
                                            const float* __restrict__ w2,
                                            const float* __restrict__ b2,
                                            float* __restrict__ z) {
    int b = blockIdx.x, tid = threadIdx.x;
    __shared__ float sl[NC], hl[NBC];
    if (tid < NC) sl[tid] = s[b * NC + tid];
    __syncthreads();
    if (tid < NBC) {
        float acc = b1[tid];
        for (int c = 0; c < NC; ++c) acc = fmaf(w1[tid * NC + c], sl[c], acc);
        hl[tid] = fmaxf(acc, 0.f);
    }
    __syncthreads();
    if (tid < NC) {
        float acc = b2[tid];
        for (int j = 0; j < NBC; ++j) acc = fmaf(w2[tid * NBC + j], hl[j], acc);
        z[b * NC + tid] = 1.f / (1.f + expf(-acc));
    }
}

// ---- K3c: per-b SE-folded pointwise weights Wse[b][o][c] ----
__global__ __launch_bounds__(256) void k_pww(const float* __restrict__ z,
                                             const float* __restrict__ pa_w,
                                             const float* __restrict__ pb_w,
                                             const float* __restrict__ pc_w,
                                             const float* __restrict__ pd_w,
                                             unsigned short* __restrict__ wse) {
    int i = blockIdx.x * 256 + threadIdx.x;
    if (i >= NB * NC * NC) return;
    int b = i / (NC * NC), rem = i % (NC * NC);
    int o = rem / NC, c = rem % NC;
    int br = o / NBC, lc = o % NBC;
    const float* P = (br == 0) ? pa_w : (br == 1) ? pb_w : (br == 2) ? pc_w : pd_w;
    wse[i] = f2bf(P[lc * NC + c] * z[b * NC + c]);
}

// ---- K4: u(bf16) = bn(Wse @ x3) [+hswish for branches a,b]  (MFMA) ----
__global__ __launch_bounds__(256) void k_pwg(const unsigned short* __restrict__ x3,
                                             const unsigned short* __restrict__ wse,
                                             const float* __restrict__ pa_bn,
                                             const float* __restrict__ pb_bn,
                                             const float* __restrict__ pc_bn,
                                             const float* __restrict__ pd_bn,
                                             unsigned short* __restrict__ u) {
    int blk = blockIdx.x;
    int b = blk / 50;
    int n0 = (blk % 50) * 128;
    int tid = threadIdx.x;
    __shared__ __align__(16) unsigned short Wpan[3][NC][APAD];
    __shared__ __align__(16) unsigned short Xp[128 * APAD];
    int lane = tid & 63, wv = tid >> 6;
    int lr = lane & 15, kg = lane >> 4;
    f32x4 acc[6][2];
#pragma unroll
    for (int mt = 0; mt < 6; ++mt)
#pragma unroll
        for (int nn = 0; nn < 2; ++nn) acc[mt][nn] = (f32x4){0.f, 0.f, 0.f, 0.f};

    const unsigned short* wb = wse + (size_t)b * NC * NC;
    for (int i = tid; i < 3 * NC * 4; i += 256) {
        int kt = i / (NC * 4), rem = i % (NC * 4);
        int o = rem >> 2, s4 = rem & 3;
        *(bf16x8*)&Wpan[kt][o][s4 * 8] = *(const bf16x8*)(wb + o * NC + kt * 32 + s4 * 8);
    }

    int kp = tid >> 4;
    int seg = tid & 15;
    const unsigned short* x3b = x3 + (size_t)b * NC * NN;

    for (int kt = 0; kt < 3; ++kt) {
        int k0 = kt * 32;
        {
            const unsigned short* src0 = x3b + (size_t)(k0 + 2 * kp) * NN + n0 + seg * 8;
            bf16x8 va = *(const bf16x8*)src0;
            bf16x8 vb = *(const bf16x8*)(src0 + NN);
            char* base = (char*)&Xp[0];
#pragma unroll
            for (int e = 0; e < 8; ++e) {
                int n = seg * 8 + e;
                int g = (kp >> 2) ^ (n & 3) ^ ((n >> 3) & 3);
                unsigned pk = (unsigned)(unsigned short)va[e] |
                              ((unsigned)(unsigned short)vb[e] << 16);
                *(unsigned*)(base + n * 80 + g * 16 + (kp & 3) * 4) = pk;
            }
        }
        __syncthreads();
        bf16x8 afr[6];
#pragma unroll
        for (int mt = 0; mt < 6; ++mt)
            afr[mt] = *(const bf16x8*)&Wpan[kt][mt * 16 + lr][kg * 8];
#pragma unroll
        for (int nn = 0; nn < 2; ++nn) {
            int nl = (wv * 2 + nn) * 16 + lr;
            int g = kg ^ (nl & 3) ^ ((nl >> 3) & 3);
            bf16x8 bb = *(const bf16x8*)((const char*)&Xp[0] + nl * 80 + g * 16);
#pragma unroll
            for (int mt = 0; mt < 6; ++mt)
                acc[mt][nn] = __builtin_amdgcn_mfma_f32_16x16x32_bf16(afr[mt], bb, acc[mt][nn], 0, 0, 0);
        }
        __syncthreads();
    }
#pragma unroll
    for (int mt = 0; mt < 6; ++mt)
#pragma unroll
        for (int nn = 0; nn < 2; ++nn) {
            int n = n0 + (wv * 2 + nn) * 16 + lr;
#pragma unroll
            for (int i = 0; i < 4; ++i) {
                int o = mt * 16 + kg * 4 + i;
                int br = o / NBC, lc = o % NBC;
                const float* bnp = (br == 0) ? pa_bn : (br == 1) ? pb_bn
                                 : (br == 2) ? pc_bn : pd_bn;
                float val = bnval(acc[mt][nn][i], bnp, NBC, lc);
                if (br < 2) val = hswish(val);
                u[((size_t)b * NC + o) * NN + n] = f2bf(val);
            }
        }
}

// ---- K5: temporal convs / maxpool / identity + residual + hswish -> out ----
__global__ __launch_bounds__(256) void k_tcn(const unsigned short* __restrict__ u,
                                             const float* __restrict__ x,
                                             const float* __restrict__ ta_w, const float* __restrict__ ta_bn,
                                             const float* __restrict__ tb_w, const float* __restrict__ tb_bn,
                                             float* __restrict__ out) {
    size_t gid = (size_t)blockIdx.x * 256 + threadIdx.x;
    if (gid >= (size_t)NB * NC * NT * NV) return;
    int v = gid % NV;
    size_t r = gid / NV;
    int t = r % NT; r /= NT;
    int oc = r % NC;
    int b = r / NC;
    int br = oc / NBC, lc = oc % NBC;
    float val;
    if (br == 0) {
        float acc = 0.f;
        for (int i = 0; i < 3; ++i) {
            int tt = t - 1 + i;
            if ((unsigned)tt < (unsigned)NT) {
                const unsigned short* up = u + (((size_t)b * NC) * NT + tt) * NV + v;
                for (int c2 = 0; c2 < NBC; ++c2)
                    acc = fmaf(ta_w[(lc * NBC + c2) * 3 + i], bf2f(up[(size_t)c2 * NT * NV]), acc);
            }
        }
        val = bnval(acc, ta_bn, NBC, lc);
    } else if (br == 1) {
        float acc = 0.f;
        for (int i = 0; i < 3; ++i) {
            int tt = t - 2 + 2 * i;
            if ((unsigned)tt < (unsigned)NT) {
                const unsigned short* up = u + (((size_t)b * NC + NBC) * NT + tt) * NV + v;
                for (int c2 = 0; c2 < NBC; ++c2)
                    acc = fmaf(tb_w[(lc * NBC + c2) * 3 + i], bf2f(up[(size_t)c2 * NT * NV]), acc);
            }
        }
        val = bnval(acc, tb_bn, NBC, lc);
    } else if (br == 2) {
        float m = -INFINITY;
        for (int dt = -1; dt <= 1; ++dt) {
            int tt = t + dt;
            if ((unsigned)tt < (unsigned)NT)
                m = fmaxf(m, bf2f(u[(((size_t)b * NC + 2 * NBC + lc) * NT + tt) * NV + v]));
        }
        val = m;
    } else {
        val = bf2f(u[(((size_t)b * NC + 3 * NBC + lc) * NT + t) * NV + v]);
    }
    float sres = val + x[gid];
    out[gid] = hswish(sres);
}

extern "C" void kernel_launch(void* const* d_in, const int* in_sizes, int n_in,
                              void* d_out, int out_size, void* d_ws, size_t ws_size,
                              hipStream_t stream) {
    const float* x = (const float*)d_in[0];
    const int* intra = (const int*)d_in[1];
    const int* inter = (const int*)d_in[2];
    const float* A_gcn = (const float*)d_in[3];
    const float* W_gcn = (const float*)d_in[4];
    const float* gcn_bn = (const float*)d_in[5];
    const float* Wp = (const float*)d_in[6];
    const float* W_adyn = (const float*)d_in[7];
    const float* gate = (const float*)d_in[8];
    const float* se_w1 = (const float*)d_in[9];
    const float* se_b1 = (const float*)d_in[10];
    const float* se_w2 = (const float*)d_in[11];
    const float* se_b2 = (const float*)d_in[12];
    const float* pa_w = (const float*)d_in[13];
    const float* pa_bn = (const float*)d_in[14];
    const float* ta_w = (const float*)d_in[15];
    const float* ta_bn = (const float*)d_in[16];
    const float* pb_w = (const float*)d_in[17];
    const float* pb_bn = (const float*)d_in[18];
    const float* tb_w = (const float*)d_in[19];
    const float* tb_bn = (const float*)d_in[20];
    const float* pc_w = (const float*)d_in[21];
    const float* pc_bn = (const float*)d_in[22];
    const float* pd_w = (const float*)d_in[23];
    const float* pd_bn = (const float*)d_in[24];
    float* out = (float*)d_out;

    // workspace layout (bytes, every slice 16B-aligned)
    char* wsb = (char*)d_ws;
    const size_t ELEMS = (size_t)NB * NC * NT * NV;        // 19,660,800
    unsigned short* x3 = (unsigned short*)wsb;                       // 2*ELEMS B
    unsigned short* u = x3 + ELEMS;                                  // 2*ELEMS B
    float* xm = (float*)(u + ELEMS);                                 // 307,200 B
    float* sb = xm + NB * NC * NV;                                   // 12,288 B
    float* zb = sb + NB * NC;                                        // 12,288 B
    unsigned short* wcat = (unsigned short*)(zb + NB * NC);          // 73,728 B
    unsigned short* acat = wcat + NC * NK4;                          // 286,720 B
    unsigned short* wse = acat + NB * ACOLS * APAD;                  // 589,824 B
    unsigned short* xabuf = wse + (size_t)NB * NC * NC;              // chunk*4,915,200 B
    size_t base_bytes = (char*)xabuf - wsb;

    int chunk = 1;
    const int cands[6] = {32, 16, 8, 4, 2, 1};
    for (int ci = 0; ci < 6; ++ci) {
        size_t need = base_bytes + (size_t)cands[ci] * NK4 * NN * 2;
        if (need <= ws_size) { chunk = cands[ci]; break; }
    }

    k_mean<<<NB * NC, 256, 0, stream>>>(x, xm);
    k_adyn<<<NB, 256, 0, stream>>>(xm, Wp, intra, inter, A_gcn, gate, acat);
    k_wcat<<<(NC * NK4 + 255) / 256, 256, 0, stream>>>(W_gcn, W_adyn, wcat);
    for (int b0 = 0; b0 < NB; b0 += chunk) {
        k_xa<<<chunk * 384, 256, 0, stream>>>(x, intra, inter, acat, xabuf, b0);
        k_gemm<<<chunk * 50, 256, 0, stream>>>(xabuf, wcat, gcn_bn, x3, b0);
    }
    k_sred<<<NB * NC, 256, 0, stream>>>(x3, sb);
    k_se<<<NB, 128, 0, stream>>>(sb, se_w1, se_b1, se_w2, se_b2, zb);
    k_pww<<<(NB * NC * NC + 255) / 256, 256, 0, stream>>>(zb, pa_w, pb_w, pc_w, pd_w, wse);
    k_pwg<<<NB * 50, 256, 0, stream>>>(x3, wse, pa_bn, pb_bn, pc_bn, pd_bn, u);
    int total = (int)((size_t)NB * NC * NT * NV);
    k_tcn<<<(total + 255) / 256, 256, 0, stream>>>(u, x, ta_w, ta_bn, tb_w, tb_bn, out);
}

// Round 4
// 350.328 us; speedup vs baseline: 5.8724x; 1.2864x over previous
//
#include <hip/hip_runtime.h>
#include <math.h>

#define NB 32
#define NC 96
#define NT 256
#define NV 25
#define NBC 24
#define NE 24
#define CV (NC * NV)          // 2400
#define EV (NE * NV)          // 600
#define NK4 384               // 4*NC  (stage-B K)
#define NN 6400               // NT*NV (stage-B N per batch)
#define ACOLS 112             // padded (j,w) columns (100 -> 112)
#define APAD 40               // padded K stride in shorts (32 -> 40, conflict-free)

typedef __attribute__((ext_vector_type(8))) short bf16x8;
typedef __attribute__((ext_vector_type(4))) float f32x4;

__device__ __forceinline__ float hswish(float x) {
    return x * fminf(fmaxf(x + 3.f, 0.f), 6.f) * (1.f / 6.f);
}
__device__ __forceinline__ float bnval(float x, const float* p, int n, int c) {
    // p layout [4][n]: gamma, beta, rm, rv
    return (x - p[2 * n + c]) * p[c] * rsqrtf(p[3 * n + c] + 1e-5f) + p[n + c];
}
__device__ __forceinline__ unsigned short f2bf(float f) {
    unsigned u = __float_as_uint(f);
    u += 0x7fffu + ((u >> 16) & 1u);   // RNE
    return (unsigned short)(u >> 16);
}
__device__ __forceinline__ float bf2f(unsigned short us) {
    return __uint_as_float((unsigned)us << 16);
}

// ---- K1a: xmean[b,c,v] = mean_t x[b,c,t,v] ----
__global__ __launch_bounds__(256) void k_mean(const float* __restrict__ x,
                                              float* __restrict__ xm) {
    int bc = blockIdx.x;
    int tid = threadIdx.x;
    const float* xp = x + (size_t)bc * NT * NV + (size_t)tid * NV;
    float a[NV];
#pragma unroll
    for (int v = 0; v < NV; ++v) a[v] = xp[v];
    __shared__ float part[4][NV];
    int lane = tid & 63, wid = tid >> 6;
#pragma unroll
    for (int v = 0; v < NV; ++v) {
        float val = a[v];
        for (int off = 32; off > 0; off >>= 1) val += __shfl_down(val, off, 64);
        if (lane == 0) part[wid][v] = val;
    }
    __syncthreads();
    if (tid < NV) {
        float s = part[0][tid] + part[1][tid] + part[2][tid] + part[3][tid];
        xm[bc * NV + tid] = s * (1.0f / NT);
    }
}

// ---- K1b: dynamic adjacency -> fused Acat^T (bf16, padded) ----
__global__ __launch_bounds__(256) void k_adyn(const float* __restrict__ xm,
                                              const float* __restrict__ Wp,
                                              const int* __restrict__ intra,
                                              const int* __restrict__ inter,
                                              const float* __restrict__ Agcn,
                                              const float* __restrict__ gate,
                                              unsigned short* __restrict__ acat) {
    int b = blockIdx.x, tid = threadIdx.x;
    __shared__ float xms[CV];
    __shared__ float embs[EV];
    __shared__ float nrm[NV];
    __shared__ float Ads[NV * NV];
    for (int i = tid; i < CV; i += 256) xms[i] = xm[b * CV + i];
    __syncthreads();
    for (int i = tid; i < EV; i += 256) {
        int e = i / NV, v = i % NV;
        int iv = intra[v], ev2 = inter[v];
        float acc = 0.f;
        for (int c = 0; c < NC; ++c) {
            int s0 = (c < NC / 2) ? iv : ev2;
            int col = (s0 + c) % NV;
            acc = fmaf(xms[c * NV + col], Wp[e * NC + c], acc);
        }
        embs[e * NV + v] = acc;
    }
    __syncthreads();
    if (tid < NV) {
        float acc = 0.f;
        for (int e = 0; e < NE; ++e) {
            float t = embs[e * NV + tid];
            acc = fmaf(t, t, acc);
        }
        nrm[tid] = sqrtf(acc) + 1e-12f;
    }
    __syncthreads();
    for (int i = tid; i < NV * NV; i += 256) {
        int v = i / NV, w = i % NV;
        float acc = 0.f;
        for (int e = 0; e < NE; ++e)
            acc = fmaf(embs[e * NV + v], embs[e * NV + w], acc);
        Ads[i] = acc / (nrm[v] * nrm[w]);
    }
    __syncthreads();
    float sg = 1.f / (1.f + expf(-gate[0]));
    for (int i = tid; i < ACOLS * APAD; i += 256) {
        int col = i / APAD, v = i % APAD;
        float val = 0.f;
        if (col < 100 && v < NV) {
            int j = col / NV, w = col % NV;
            if (j < 3) val = Agcn[(j * NV + v) * NV + w] * (1.f / 3.f);
            else val = sg * Ads[v * NV + w];
        }
        acat[(size_t)b * ACOLS * APAD + i] = f2bf(val);
    }
}

// ---- K1c: Wcat bf16 [o=96][kc=(j,c) 384] ----
__global__ __launch_bounds__(256) void k_wcat(const float* __restrict__ Wg,
                                              const float* __restrict__ Wa,
                                              unsigned short* __restrict__ wcat) {
    int i = blockIdx.x * 256 + threadIdx.x;
    if (i >= NC * NK4) return;
    int o = i / NK4, kc = i % NK4;
    int j = kc / NC, c = kc % NC;
    float v = (j < 3) ? Wg[(j * NC + o) * NC + c] : Wa[o * NC + c];
    wcat[i] = f2bf(v);
}

// ---- K2a: Xa[(j,c),(t,w)] = X_sh[(c,t),v] @ AcatT  (MFMA) ----
__global__ __launch_bounds__(256) void k_xa(const float* __restrict__ x,
                                            const int* __restrict__ intra,
                                            const int* __restrict__ inter,
                                            const unsigned short* __restrict__ acat,
                                            unsigned short* __restrict__ xa, int b0) {
    int blk = blockIdx.x;
    int b = b0 + blk / 384;
    int r0 = (blk % 384) * 64;      // 64 rows of (c,t), r = c*256 + t
    int tid = threadIdx.x;
    __shared__ __align__(16) unsigned short Xs[64][APAD];
    __shared__ __align__(16) unsigned short Bs[ACOLS][APAD];
    {
        const bf16x8* src = (const bf16x8*)(acat + (size_t)b * ACOLS * APAD);
        bf16x8* dst = (bf16x8*)&Bs[0][0];
        for (int i = tid; i < ACOLS * APAD / 8; i += 256) dst[i] = src[i];
    }
    for (int i = tid; i < 64 * APAD; i += 256) {
        int row = i / APAD, v = i % APAD;
        unsigned short val = 0;
        if (v < NV) {
            int r = r0 + row;
            int c = r >> 8, t = r & 255;
            int s0 = (c < NC / 2) ? intra[v] : inter[v];
            int col = (s0 + c) % NV;
            val = f2bf(x[(((size_t)b * NC + c) * NT + t) * NV + col]);
        }
        Xs[row][v] = val;
    }
    __syncthreads();
    int lane = tid & 63, wv = tid >> 6;
    int lr = lane & 15, kg = lane >> 4;
    bf16x8 a = *(const bf16x8*)&Xs[wv * 16 + lr][kg * 8];
    f32x4 acc[7];
#pragma unroll
    for (int nt = 0; nt < 7; ++nt) {
        f32x4 z = {0.f, 0.f, 0.f, 0.f};
        bf16x8 bb = *(const bf16x8*)&Bs[nt * 16 + lr][kg * 8];
        acc[nt] = __builtin_amdgcn_mfma_f32_16x16x32_bf16(a, bb, z, 0, 0, 0);
    }
#pragma unroll
    for (int nt = 0; nt < 7; ++nt) {
        int colbase = nt * 16 + lr;
        if (colbase < 100) {
            int j = colbase / NV, w = colbase % NV;
#pragma unroll
            for (int i = 0; i < 4; ++i) {
                int r = r0 + wv * 16 + kg * 4 + i;
                int c = r >> 8, t = r & 255;
                xa[((size_t)b * NK4 + j * NC + c) * NN + t * NV + w] = f2bf(acc[nt][i]);
            }
        }
    }
}

// ---- K2b: x3(bf16) = hswish(bn(Wcat @ Xa)) ----
__global__ __launch_bounds__(256) void k_gemm(const unsigned short* __restrict__ xa,
                                              const unsigned short* __restrict__ wcat,
                                              const float* __restrict__ gbn,
                                              unsigned short* __restrict__ x3, int b0) {
    int blk = blockIdx.x;
    int b = b0 + blk / 50;
    int n0 = (blk % 50) * 128;
    int tid = threadIdx.x;
    __shared__ __align__(16) unsigned short Wpan[NC][APAD];
    __shared__ __align__(16) unsigned short Xp[128 * APAD];
    int lane = tid & 63, wv = tid >> 6;
    int lr = lane & 15, kg = lane >> 4;
    f32x4 acc[6][2];
#pragma unroll
    for (int mt = 0; mt < 6; ++mt)
#pragma unroll
        for (int nn = 0; nn < 2; ++nn) acc[mt][nn] = (f32x4){0.f, 0.f, 0.f, 0.f};

    int kp = tid >> 4;
    int seg = tid & 15;

    for (int kt = 0; kt < 12; ++kt) {
        int k0 = kt * 32;
        for (int i = tid; i < 384; i += 256) {
            int o = i >> 2, s4 = i & 3;
            *(bf16x8*)&Wpan[o][s4 * 8] = *(const bf16x8*)(wcat + o * NK4 + k0 + s4 * 8);
        }
        {
            const unsigned short* src0 = xa + ((size_t)b * NK4 + k0 + 2 * kp) * NN + n0 + seg * 8;
            bf16x8 va = *(const bf16x8*)src0;
            bf16x8 vb = *(const bf16x8*)(src0 + NN);
            char* base = (char*)&Xp[0];
#pragma unroll
            for (int e = 0; e < 8; ++e) {
                int n = seg * 8 + e;
                int g = (kp >> 2) ^ (n & 3) ^ ((n >> 3) & 3);
                unsigned pk = (unsigned)(unsigned short)va[e] |
                              ((unsigned)(unsigned short)vb[e] << 16);
                *(unsigned*)(base + n * 80 + g * 16 + (kp & 3) * 4) = pk;
            }
        }
        __syncthreads();
        bf16x8 afr[6];
#pragma unroll
        for (int mt = 0; mt < 6; ++mt)
            afr[mt] = *(const bf16x8*)&Wpan[mt * 16 + lr][kg * 8];
#pragma unroll
        for (int nn = 0; nn < 2; ++nn) {
            int nl = (wv * 2 + nn) * 16 + lr;
            int g = kg ^ (nl & 3) ^ ((nl >> 3) & 3);
            bf16x8 bb = *(const bf16x8*)((const char*)&Xp[0] + nl * 80 + g * 16);
#pragma unroll
            for (int mt = 0; mt < 6; ++mt)
                acc[mt][nn] = __builtin_amdgcn_mfma_f32_16x16x32_bf16(afr[mt], bb, acc[mt][nn], 0, 0, 0);
        }
        __syncthreads();
    }
#pragma unroll
    for (int mt = 0; mt < 6; ++mt)
#pragma unroll
        for (int nn = 0; nn < 2; ++nn) {
            int n = n0 + (wv * 2 + nn) * 16 + lr;
#pragma unroll
            for (int i = 0; i < 4; ++i) {
                int o = mt * 16 + kg * 4 + i;
                float val = acc[mt][nn][i];
                val = hswish(bnval(val, gbn, NC, o));
                x3[((size_t)b * NC + o) * NN + n] = f2bf(val);
            }
        }
}

// ---- K3a: s[b,c] = mean_{t,v} x3 (bf16 in) ----
__global__ __launch_bounds__(256) void k_sred(const unsigned short* __restrict__ x3,
                                              float* __restrict__ s) {
    int bc = blockIdx.x, tid = threadIdx.x;
    const unsigned short* p = x3 + (size_t)bc * NT * NV;
    float acc = 0.f;
    for (int i = tid; i < NN / 8; i += 256) {
        bf16x8 v = *(const bf16x8*)(p + i * 8);
#pragma unroll
        for (int e = 0; e < 8; ++e) acc += bf2f((unsigned short)v[e]);
    }
    for (int off = 32; off > 0; off >>= 1) acc += __shfl_down(acc, off, 64);
    __shared__ float part[4];
    if ((tid & 63) == 0) part[tid >> 6] = acc;
    __syncthreads();
    if (tid == 0) s[bc] = (part[0] + part[1] + part[2] + part[3]) / (float)(NT * NV);
}

// ---- K3b: SE MLP -> z[b,c] ----
__global__ __launch_bounds__(128) void k_se(const float* __restrict__ s,
                                            const float* __restrict__ w1,
                                            const float* __restrict__ b1,
                                            const float* __restrict__ w2,
                                            const float* __restrict__ b2,
                                            float* __restrict__ z) {
    int b = blockIdx.x, tid = threadIdx.x;
    __shared__ float sl[NC], hl[NBC];
    if (tid < NC) sl[tid] = s[b * NC + tid];
    __syncthreads();
    if (tid < NBC) {
        float acc = b1[tid];
        for (int c = 0; c < NC; ++c) acc = fmaf(w1[tid * NC + c], sl[c], acc);
        hl[tid] = fmaxf(acc, 0.f);
    }
    __syncthreads();
    if (tid < NC) {
        float acc = b2[tid];
        for (int j = 0; j < NBC; ++j) acc = fmaf(w2[tid * NBC + j], hl[j], acc);
        z[b * NC + tid] = 1.f / (1.f + expf(-acc));
    }
}

// ---- K3c: per-b SE-folded pointwise weights Wse[b][o][c] ----
__global__ __launch_bounds__(256) void k_pww(const float* __restrict__ z,
                                             const float* __restrict__ pa_w,
                                             const float* __restrict__ pb_w,
                                             const float* __restrict__ pc_w,
                                             const float* __restrict__ pd_w,
                                             unsigned short* __restrict__ wse) {
    int i = blockIdx.x * 256 + threadIdx.x;
    if (i >= NB * NC * NC) return;
    int b = i / (NC * NC), rem = i % (NC * NC);
    int o = rem / NC, c = rem % NC;
    int br = o / NBC, lc = o % NBC;
    const float* P = (br == 0) ? pa_w : (br == 1) ? pb_w : (br == 2) ? pc_w : pd_w;
    wse[i] = f2bf(P[lc * NC + c] * z[b * NC + c]);
}

// ---- K4: u(bf16) = bn(Wse @ x3) [+hswish for branches a,b]  (MFMA) ----
__global__ __launch_bounds__(256) void k_pwg(const unsigned short* __restrict__ x3,
                                             const unsigned short* __restrict__ wse,
                                             const float* __restrict__ pa_bn,
                                             const float* __restrict__ pb_bn,
                                             const float* __restrict__ pc_bn,
                                             const float* __restrict__ pd_bn,
                                             unsigned short* __restrict__ u) {
    int blk = blockIdx.x;
    int b = blk / 50;
    int n0 = (blk % 50) * 128;
    int tid = threadIdx.x;
    __shared__ __align__(16) unsigned short Wpan[3][NC][APAD];
    __shared__ __align__(16) unsigned short Xp[128 * APAD];
    int lane = tid & 63, wv = tid >> 6;
    int lr = lane & 15, kg = lane >> 4;
    f32x4 acc[6][2];
#pragma unroll
    for (int mt = 0; mt < 6; ++mt)
#pragma unroll
        for (int nn = 0; nn < 2; ++nn) acc[mt][nn] = (f32x4){0.f, 0.f, 0.f, 0.f};

    const unsigned short* wb = wse + (size_t)b * NC * NC;
    for (int i = tid; i < 3 * NC * 4; i += 256) {
        int kt = i / (NC * 4), rem = i % (NC * 4);
        int o = rem >> 2, s4 = rem & 3;
        *(bf16x8*)&Wpan[kt][o][s4 * 8] = *(const bf16x8*)(wb + o * NC + kt * 32 + s4 * 8);
    }

    int kp = tid >> 4;
    int seg = tid & 15;
    const unsigned short* x3b = x3 + (size_t)b * NC * NN;

    for (int kt = 0; kt < 3; ++kt) {
        int k0 = kt * 32;
        {
            const unsigned short* src0 = x3b + (size_t)(k0 + 2 * kp) * NN + n0 + seg * 8;
            bf16x8 va = *(const bf16x8*)src0;
            bf16x8 vb = *(const bf16x8*)(src0 + NN);
            char* base = (char*)&Xp[0];
#pragma unroll
            for (int e = 0; e < 8; ++e) {
                int n = seg * 8 + e;
                int g = (kp >> 2) ^ (n & 3) ^ ((n >> 3) & 3);
                unsigned pk = (unsigned)(unsigned short)va[e] |
                              ((unsigned)(unsigned short)vb[e] << 16);
                *(unsigned*)(base + n * 80 + g * 16 + (kp & 3) * 4) = pk;
            }
        }
        __syncthreads();
        bf16x8 afr[6];
#pragma unroll
        for (int mt = 0; mt < 6; ++mt)
            afr[mt] = *(const bf16x8*)&Wpan[kt][mt * 16 + lr][kg * 8];
#pragma unroll
        for (int nn = 0; nn < 2; ++nn) {
            int nl = (wv * 2 + nn) * 16 + lr;
            int g = kg ^ (nl & 3) ^ ((nl >> 3) & 3);
            bf16x8 bb = *(const bf16x8*)((const char*)&Xp[0] + nl * 80 + g * 16);
#pragma unroll
            for (int mt = 0; mt < 6; ++mt)
                acc[mt][nn] = __builtin_amdgcn_mfma_f32_16x16x32_bf16(afr[mt], bb, acc[mt][nn], 0, 0, 0);
        }
        __syncthreads();
    }
#pragma unroll
    for (int mt = 0; mt < 6; ++mt)
#pragma unroll
        for (int nn = 0; nn < 2; ++nn) {
            int n = n0 + (wv * 2 + nn) * 16 + lr;
#pragma unroll
            for (int i = 0; i < 4; ++i) {
                int o = mt * 16 + kg * 4 + i;
                int br = o / NBC, lc = o % NBC;
                const float* bnp = (br == 0) ? pa_bn : (br == 1) ? pb_bn
                                 : (br == 2) ? pc_bn : pd_bn;
                float val = bnval(acc[mt][nn][i], bnp, NBC, lc);
                if (br < 2) val = hswish(val);
                u[((size_t)b * NC + o) * NN + n] = f2bf(val);
            }
        }
}

// ---- K5: MFMA temporal convs + maxpool + identity + residual + hswish ----
// per (b, 128-n chunk). Taps are +-25 (dil1) / +-50 (dil2) shifts in n.
__global__ __launch_bounds__(256) void k_tcnm(const unsigned short* __restrict__ u,
                                              const float* __restrict__ x,
                                              const float* __restrict__ ta_w, const float* __restrict__ ta_bn,
                                              const float* __restrict__ tb_w, const float* __restrict__ tb_bn,
                                              float* __restrict__ out) {
    int blk = blockIdx.x;
    int b = blk / 50, n0 = (blk % 50) * 128;
    int tid = threadIdx.x;
    __shared__ __align__(16) unsigned short Us[48][264];   // window [n0-64, n0+200)
    __shared__ __align__(16) unsigned short Wl[2][32][104]; // A panels, k = c2*3+i (72, pad 96+)
    // build A panels
    for (int i = tid; i < 2 * 32 * 104; i += 256) {
        int br = i / (32 * 104), rem = i % (32 * 104);
        int o = rem / 104, kk = rem % 104;
        float v = 0.f;
        if (o < 24 && kk < 72) {
            int c2 = kk / 3, i3 = kk % 3;
            v = (br ? tb_w : ta_w)[(o * 24 + c2) * 3 + i3];
        }
        Wl[br][o][kk] = f2bf(v);
    }
    // stage conv input channels 0..47, zero-filled outside [0, NN)
    int wn = n0 - 64;
    const unsigned short* ub = u + (size_t)b * NC * NN;
    for (int idx = tid; idx < 48 * 33; idx += 256) {
        int c2 = idx / 33, jv = idx % 33;
        int j = jv * 8, n = wn + j;
        bf16x8 val;
        if (n >= 0 && n + 7 < NN) {
            val = *(const bf16x8*)(ub + (size_t)c2 * NN + n);
        } else {
#pragma unroll
            for (int e = 0; e < 8; ++e) {
                int ne = n + e;
                val[e] = (ne >= 0 && ne < NN) ? (short)ub[(size_t)c2 * NN + ne] : (short)0;
            }
        }
        *(bf16x8*)&Us[c2][j] = val;
    }
    __syncthreads();

    int lane = tid & 63, wave = tid >> 6;
    int lr = lane & 15, kg = lane >> 4;
    int br = wave >> 1, mh = wave & 1;     // branch (a/b), m-half
    int dn = 25 + br * 25;                  // tap stride in n
    bf16x8 af[3];
#pragma unroll
    for (int kt = 0; kt < 3; ++kt)
        af[kt] = *(const bf16x8*)&Wl[br][mh * 16 + lr][kt * 32 + kg * 8];
    f32x4 acc[8];
#pragma unroll
    for (int nt = 0; nt < 8; ++nt) acc[nt] = (f32x4){0.f, 0.f, 0.f, 0.f};
#pragma unroll
    for (int kt = 0; kt < 3; ++kt) {
        int kbase = kt * 32 + kg * 8;
#pragma unroll
        for (int nt = 0; nt < 8; ++nt) {
            int nl = nt * 16 + lr;
            bf16x8 bb;
#pragma unroll
            for (int e = 0; e < 8; ++e) {
                int k = kbase + e;
                unsigned short v = 0;
                if (k < 72) {
                    int c2 = k / 3, i3 = k - 3 * c2;
                    v = Us[br * 24 + c2][nl + 64 + (i3 - 1) * dn];
                }
                bb[e] = (short)v;
            }
            acc[nt] = __builtin_amdgcn_mfma_f32_16x16x32_bf16(af[kt], bb, acc[nt], 0, 0, 0);
        }
    }
    // epilogue: conv branches a,b
    const float* bnp = br ? tb_bn : ta_bn;
    int ml = mh * 16 + kg * 4;
#pragma unroll
    for (int ii = 0; ii < 4; ++ii) {
        int ol = ml + ii;
        if (ol < 24) {
            int oc = br * 24 + ol;
#pragma unroll
            for (int nt = 0; nt < 8; ++nt) {
                size_t n = (size_t)n0 + nt * 16 + lr;
                float val = bnval(acc[nt][ii], bnp, NBC, ol);
                size_t gi = ((size_t)b * NC + oc) * NN + n;
                out[gi] = hswish(val + x[gi]);
            }
        }
    }
    // epilogue: maxpool (ch 48..71) + identity (ch 72..95)
    for (int it = 0; it < 24; ++it) {
        int idx = it * 256 + tid;          // 0..6143: [48 ch][128 n]
        int ch = idx >> 7, nl2 = idx & 127;
        int n = n0 + nl2;
        float val;
        const unsigned short* up = ub + (size_t)(48 + ch) * NN + n;
        if (ch < 24) {
            float m = bf2f(up[0]);
            if (n >= 25) m = fmaxf(m, bf2f(up[-25]));
            if (n < NN - 25) m = fmaxf(m, bf2f(up[25]));
            val = m;
        } else {
            val = bf2f(up[0]);
        }
        size_t gi = ((size_t)b * NC + 48 + ch) * NN + n;
        out[gi] = hswish(val + x[gi]);
    }
}

extern "C" void kernel_launch(void* const* d_in, const int* in_sizes, int n_in,
                              void* d_out, int out_size, void* d_ws, size_t ws_size,
                              hipStream_t stream) {
    const float* x = (const float*)d_in[0];
    const int* intra = (const int*)d_in[1];
    const int* inter = (const int*)d_in[2];
    const float* A_gcn = (const float*)d_in[3];
    const float* W_gcn = (const float*)d_in[4];
    const float* gcn_bn = (const float*)d_in[5];
    const float* Wp = (const float*)d_in[6];
    const float* W_adyn = (const float*)d_in[7];
    const float* gate = (const float*)d_in[8];
    const float* se_w1 = (const float*)d_in[9];
    const float* se_b1 = (const float*)d_in[10];
    const float* se_w2 = (const float*)d_in[11];
    const float* se_b2 = (const float*)d_in[12];
    const float* pa_w = (const float*)d_in[13];
    const float* pa_bn = (const float*)d_in[14];
    const float* ta_w = (const float*)d_in[15];
    const float* ta_bn = (const float*)d_in[16];
    const float* pb_w = (const float*)d_in[17];
    const float* pb_bn = (const float*)d_in[18];
    const float* tb_w = (const float*)d_in[19];
    const float* tb_bn = (const float*)d_in[20];
    const float* pc_w = (const float*)d_in[21];
    const float* pc_bn = (const float*)d_in[22];
    const float* pd_w = (const float*)d_in[23];
    const float* pd_bn = (const float*)d_in[24];
    float* out = (float*)d_out;

    // workspace layout (bytes, every slice 16B-aligned)
    char* wsb = (char*)d_ws;
    const size_t ELEMS = (size_t)NB * NC * NT * NV;        // 19,660,800
    unsigned short* x3 = (unsigned short*)wsb;                       // 2*ELEMS B
    unsigned short* u = x3 + ELEMS;                                  // 2*ELEMS B
    float* xm = (float*)(u + ELEMS);                                 // 307,200 B
    float* sb = xm + NB * NC * NV;                                   // 12,288 B
    float* zb = sb + NB * NC;                                        // 12,288 B
    unsigned short* wcat = (unsigned short*)(zb + NB * NC);          // 73,728 B
    unsigned short* acat = wcat + NC * NK4;                          // 286,720 B
    unsigned short* wse = acat + NB * ACOLS * APAD;                  // 589,824 B
    unsigned short* xabuf = wse + (size_t)NB * NC * NC;              // chunk*4,915,200 B
    size_t base_bytes = (char*)xabuf - wsb;

    int chunk = 1;
    const int cands[6] = {32, 16, 8, 4, 2, 1};
    for (int ci = 0; ci < 6; ++ci) {
        size_t need = base_bytes + (size_t)cands[ci] * NK4 * NN * 2;
        if (need <= ws_size) { chunk = cands[ci]; break; }
    }

    k_mean<<<NB * NC, 256, 0, stream>>>(x, xm);
    k_adyn<<<NB, 256, 0, stream>>>(xm, Wp, intra, inter, A_gcn, gate, acat);
    k_wcat<<<(NC * NK4 + 255) / 256, 256, 0, stream>>>(W_gcn, W_adyn, wcat);
    for (int b0 = 0; b0 < NB; b0 += chunk) {
        k_xa<<<chunk * 384, 256, 0, stream>>>(x, intra, inter, acat, xabuf, b0);
        k_gemm<<<chunk * 50, 256, 0, stream>>>(xabuf, wcat, gcn_bn, x3, b0);
    }
    k_sred<<<NB * NC, 256, 0, stream>>>(x3, sb);
    k_se<<<NB, 128, 0, stream>>>(sb, se_w1, se_b1, se_w2, se_b2, zb);
    k_pww<<<(NB * NC * NC + 255) / 256, 256, 0, stream>>>(zb, pa_w, pb_w, pc_w, pd_w, wse);
    k_pwg<<<NB * 50, 256, 0, stream>>>(x3, wse, pa_bn, pb_bn, pc_bn, pd_bn, u);
    k_tcnm<<<NB * 50, 256, 0, stream>>>(u, x, ta_w, ta_bn, tb_w, tb_bn, out);
}